// Round 16
// baseline (1745.101 us; speedup 1.0000x reference)
//
#include <hip/hip_runtime.h>

#define NEG_SLOPE 0.1f

static inline int cdiv(int a, int b) { return (a + b - 1) / b; }

// ======================= padded-buffer conv scheme =======================
// All intermediate tensors live in a padded layout: per (b,c) plane of logical
// H x W data, physical plane is (H+2) rows x (W+8) cols; element (h,w) at
// [(h+1)*(W+8) + (w+4)]. The 1-row/4-col ring holds zeros (maintained by
// ring_zero), so EVERY conv output slot reads unconditionally — one interior
// body (VGPR 32) covers 100% of the work, no edge kernel.
//
// Round-16: XCD batch partitioning. Round-15 counters: L6 FETCH=123MB vs 40MB
// input (3x HBM re-fetch) because z=(b,cog) ordering spreads every batch's
// input across all 8 XCD L2s. Fix: fold batch into blockIdx.x as b = x % NB.
// gridDim.x % 8 == 0 on batch-8 layers, so bid%8 == x%8 -> each XCD serves ONE
// batch (working set 40->5MB on L6, near its 4MB L2). Blocks x and x+8
// (adjacent rows, same batch) stay on the same XCD -> spatial streaming kept.
// Pure index bijection; conv body, conv_int/edge, rings byte-identical.

// ---------------- ring_zero: zero the pad ring of nplanes planes ----------------
__global__ void ring_zero(float* __restrict__ buf, int nplanes, int PH, int PW) {
    const int R = 2 * PW + (PH - 2) * 8;       // ring elems per plane
    const int total = nplanes * R;
    int idx = blockIdx.x * 256 + threadIdx.x;
    if (idx >= total) return;
    int p = idx / R, r = idx % R;
    int row, col;
    if (r < PW)           { row = 0;        col = r; }
    else if (r < 2 * PW)  { row = PH - 1;   col = r - PW; }
    else {
        int rr = r - 2 * PW;
        row = 1 + rr / 8;
        int c = rr % 8;
        col = (c < 4) ? c : (PW - 8 + c);      // left 4 cols, right 4 cols
    }
    buf[(size_t)p * PH * PW + (size_t)row * PW + col] = 0.0f;
}

// ---------------- conv over padded input (single interior-style body) -----------
// NB batches folded into blockIdx.x (b = x % NB -> XCD partition); z = co-groups.
// POUT: write into padded layout (next layer's input) or compact (final features).
template <int K, int S, int PAD, int CIN, int COUT,
          int HIN, int WIN, int HOUT, int WOUT, int TCO, int TW, int NB, bool POUT>
__global__ __launch_bounds__(256) void conv_pad(const float* __restrict__ x,
                                                const float* __restrict__ w,
                                                const float* __restrict__ bs,
                                                float* __restrict__ y) {
    constexpr int SLOTS_W = WOUT / TW;
    constexpr int NSLOT   = HOUT * SLOTS_W;
    constexpr int NW      = TCO * CIN * K * K;
    constexpr int L       = (TW - 1) * S + K;
    constexpr int ISTR    = WIN + 8;
    constexpr int IPLANE  = (HIN + 2) * ISTR;
    constexpr int OSTR    = POUT ? (WOUT + 8) : WOUT;
    constexpr int OPLANE  = POUT ? (HOUT + 2) * OSTR : HOUT * WOUT;

    __shared__ float wlds[NW];

    const int xx  = blockIdx.x;
    const int b   = xx % NB;              // XCD-aligned batch partition
    const int xbk = xx / NB;              // spatial block within the batch
    const int cob = blockIdx.z * TCO;

    for (int i = threadIdx.x; i < NW; i += 256) {
        int t    = i % TCO;
        int rest = i / TCO;
        wlds[i] = w[(size_t)(cob + t) * (CIN * K * K) + rest];
    }
    __syncthreads();

    const int slot = xbk * 256 + threadIdx.x;
    if (slot >= NSLOT) return;

    const int ho = slot / SLOTS_W;
    const int wo = (slot % SLOTS_W) * TW;

    const float* xb = x + (size_t)b * CIN * IPLANE;

    float acc[TCO][TW];
#pragma unroll
    for (int t = 0; t < TCO; ++t) {
        float bv = bs[cob + t];
#pragma unroll
        for (int j = 0; j < TW; ++j) acc[t][j] = bv;
    }

    const int hi0 = ho * S - PAD;   // may be -1: row 0 of padded plane (zeros)
    const int wi0 = wo * S - PAD;

    for (int ci = 0; ci < CIN; ++ci) {
        const float* xc = xb + (size_t)ci * IPLANE;
        const float* wc = &wlds[(ci * K * K) * TCO];
#pragma unroll
        for (int kh = 0; kh < K; ++kh) {
            const float* xr = xc + (size_t)(hi0 + kh + 1) * ISTR + (wi0 + 4);
            float r[L];
#pragma unroll
            for (int u = 0; u < L; ++u) r[u] = xr[u];
#pragma unroll
            for (int kw = 0; kw < K; ++kw) {
                const float* wg = wc + (kh * K + kw) * TCO;
                float w8[TCO];
                if constexpr ((TCO % 4) == 0) {
#pragma unroll
                    for (int t = 0; t < TCO; t += 4) {
                        float4 q = *reinterpret_cast<const float4*>(wg + t);
                        w8[t] = q.x; w8[t + 1] = q.y; w8[t + 2] = q.z; w8[t + 3] = q.w;
                    }
                } else {
#pragma unroll
                    for (int t = 0; t < TCO; ++t) w8[t] = wg[t];
                }
#pragma unroll
                for (int j = 0; j < TW; ++j) {
                    const float xv = r[kw + j * S];
#pragma unroll
                    for (int t = 0; t < TCO; ++t)
                        acc[t][j] = fmaf(xv, w8[t], acc[t][j]);
                }
            }
        }
    }

#pragma unroll
    for (int t = 0; t < TCO; ++t) {
        float* yr = y + (size_t)(b * COUT + cob + t) * OPLANE
                      + (POUT ? ((size_t)(ho + 1) * OSTR + wo + 4)
                              : ((size_t)ho * WOUT + wo));
        float v[TW];
#pragma unroll
        for (int j = 0; j < TW; ++j) {
            const float a = acc[t][j];
            v[j] = a >= 0.0f ? a : NEG_SLOPE * a;
        }
        if constexpr (TW == 4) {
            *reinterpret_cast<float4*>(yr) = make_float4(v[0], v[1], v[2], v[3]);
        } else if constexpr (TW == 2) {
            *reinterpret_cast<float2*>(yr) = make_float2(v[0], v[1]);
        } else {
#pragma unroll
            for (int j = 0; j < TW; ++j) yr[j] = v[j];
        }
    }
}

// Compile-time geometry for L1 (reads the raw, unpadded image).
template <int K, int S, int PAD, int HIN, int WIN, int HOUT, int WOUT, int TW>
struct Geom {
    static constexpr int SLOTS_W = WOUT / TW;
    static constexpr int NSLOT   = HOUT * SLOTS_W;
    static constexpr int L       = (TW - 1) * S + K;
    static constexpr int HO_LO   = (PAD + S - 1) / S;
    static constexpr int HO_HI0  = (HIN - K + PAD) / S + 1;
    static constexpr int HO_HI   = HO_HI0 < HOUT ? HO_HI0 : HOUT;
    static constexpr int WS_LO   = (PAD + TW * S - 1) / (TW * S);
    static constexpr int WS_HI0  = (WIN + PAD - L) / (TW * S) + 1;
    static constexpr int WS_HI   = WS_HI0 < SLOTS_W ? WS_HI0 : SLOTS_W;
    static constexpr int WS_N    = WS_HI - WS_LO;
    static constexpr int N_INT   = (HO_HI - HO_LO) * WS_N;
    static constexpr int N_EDGE  = NSLOT - N_INT;
};

// ---------------- L1 interior (round-3 body; padded store) -------
template <int K, int S, int PAD, int CIN, int COUT,
          int HIN, int WIN, int HOUT, int WOUT, int TCO, int TW>
__global__ __launch_bounds__(256, 4) void conv_int(const float* __restrict__ x,
                                                   const float* __restrict__ w,
                                                   const float* __restrict__ bs,
                                                   float* __restrict__ y) {
    using G = Geom<K, S, PAD, HIN, WIN, HOUT, WOUT, TW>;
    constexpr int NW     = TCO * CIN * K * K;
    constexpr int OSTR   = WOUT + 8;
    constexpr int OPLANE = (HOUT + 2) * OSTR;

    __shared__ float wlds[NW];

    const int zz  = blockIdx.z;
    const int b   = zz / (COUT / TCO);
    const int cob = (zz % (COUT / TCO)) * TCO;

    for (int i = threadIdx.x; i < NW; i += 256) {
        int t    = i % TCO;
        int rest = i / TCO;
        wlds[i] = w[(size_t)(cob + t) * (CIN * K * K) + rest];
    }
    __syncthreads();

    const int s = blockIdx.x * 256 + threadIdx.x;
    if (s >= G::N_INT) return;

    const int ho = G::HO_LO + s / G::WS_N;
    const int wo = (G::WS_LO + s % G::WS_N) * TW;

    const float* xb = x + (size_t)b * CIN * HIN * WIN;

    float acc[TCO][TW];
#pragma unroll
    for (int t = 0; t < TCO; ++t) {
        float bv = bs[cob + t];
#pragma unroll
        for (int j = 0; j < TW; ++j) acc[t][j] = bv;
    }

    const int hi0 = ho * S - PAD;
    const int wi0 = wo * S - PAD;

#pragma unroll
    for (int ci = 0; ci < CIN; ++ci) {
        const float* xc = xb + (size_t)ci * HIN * WIN;
        const float* wc = &wlds[(ci * K * K) * TCO];
#pragma unroll
        for (int kh = 0; kh < K; ++kh) {
            const float* xr = xc + (size_t)(hi0 + kh) * WIN + wi0;
            float r[G::L];
#pragma unroll
            for (int u = 0; u < G::L; ++u) r[u] = xr[u];
#pragma unroll
            for (int kw = 0; kw < K; ++kw) {
                const float* wg = wc + (kh * K + kw) * TCO;
                float w8[TCO];
                if constexpr ((TCO % 4) == 0) {
#pragma unroll
                    for (int t = 0; t < TCO; t += 4) {
                        float4 q = *reinterpret_cast<const float4*>(wg + t);
                        w8[t] = q.x; w8[t + 1] = q.y; w8[t + 2] = q.z; w8[t + 3] = q.w;
                    }
                } else {
#pragma unroll
                    for (int t = 0; t < TCO; ++t) w8[t] = wg[t];
                }
#pragma unroll
                for (int j = 0; j < TW; ++j) {
                    const float xv = r[kw + j * S];
#pragma unroll
                    for (int t = 0; t < TCO; ++t)
                        acc[t][j] = fmaf(xv, w8[t], acc[t][j]);
                }
            }
        }
    }

#pragma unroll
    for (int t = 0; t < TCO; ++t) {
        float* yr = y + (size_t)(b * COUT + cob + t) * OPLANE
                      + (size_t)(ho + 1) * OSTR + wo + 4;
        float v[TW];
#pragma unroll
        for (int j = 0; j < TW; ++j) {
            const float a = acc[t][j];
            v[j] = a >= 0.0f ? a : NEG_SLOPE * a;
        }
        if constexpr (TW == 4) {
            *reinterpret_cast<float4*>(yr) = make_float4(v[0], v[1], v[2], v[3]);
        } else {
#pragma unroll
            for (int j = 0; j < TW; ++j) yr[j] = v[j];
        }
    }
}

// ---------------- L1 edge ring (bounds-checked reads; padded store) ----------------
template <int K, int S, int PAD, int CIN, int COUT,
          int HIN, int WIN, int HOUT, int WOUT, int TCO, int TW>
__global__ __launch_bounds__(256) void conv_edge(const float* __restrict__ x,
                                                 const float* __restrict__ w,
                                                 const float* __restrict__ bs,
                                                 float* __restrict__ y) {
    using G = Geom<K, S, PAD, HIN, WIN, HOUT, WOUT, TW>;
    constexpr int SLOTS_W = G::SLOTS_W;
    constexpr int NW      = TCO * CIN * K * K;
    constexpr int OSTR    = WOUT + 8;
    constexpr int OPLANE  = (HOUT + 2) * OSTR;

    __shared__ float wlds[NW];

    const int zz  = blockIdx.z;
    const int b   = zz / (COUT / TCO);
    const int cob = (zz % (COUT / TCO)) * TCO;

    for (int i = threadIdx.x; i < NW; i += 256) {
        int t    = i % TCO;
        int rest = i / TCO;
        wlds[i] = w[(size_t)(cob + t) * (CIN * K * K) + rest];
    }
    __syncthreads();

    const int s = blockIdx.x * 256 + threadIdx.x;
    if (s >= G::N_EDGE) return;

    constexpr int TOPN = G::HO_LO * SLOTS_W;
    constexpr int BOTN = (HOUT - G::HO_HI) * SLOTS_W;
    constexpr int MIDH = G::HO_HI - G::HO_LO;
    constexpr int LW   = G::WS_LO;
    constexpr int RW   = SLOTS_W - G::WS_HI;
    constexpr int LN   = MIDH * LW;

    int ho = 0, ws = 0;
    if (s < TOPN) {
        ho = s / SLOTS_W;
        ws = s % SLOTS_W;
    } else if (s < TOPN + BOTN) {
        int t = s - TOPN;
        ho = G::HO_HI + t / SLOTS_W;
        ws = t % SLOTS_W;
    } else if (s < TOPN + BOTN + LN) {
        int t = s - TOPN - BOTN;
        constexpr int D = LW > 0 ? LW : 1;
        ho = G::HO_LO + t / D;
        ws = t % D;
    } else {
        int t = s - TOPN - BOTN - LN;
        constexpr int D = RW > 0 ? RW : 1;
        ho = G::HO_LO + t / D;
        ws = G::WS_HI + t % D;
    }
    const int wo = ws * TW;

    const float* xb = x + (size_t)b * CIN * HIN * WIN;

    float acc[TCO][TW];
#pragma unroll
    for (int t = 0; t < TCO; ++t) {
        float bv = bs[cob + t];
#pragma unroll
        for (int j = 0; j < TW; ++j) acc[t][j] = bv;
    }

    const int hi0 = ho * S - PAD;
    const int wi0 = wo * S - PAD;

#pragma unroll 2
    for (int ci = 0; ci < CIN; ++ci) {
        const float* xc = xb + (size_t)ci * HIN * WIN;
        const float* wc = &wlds[(ci * K * K) * TCO];
#pragma unroll
        for (int kh = 0; kh < K; ++kh) {
            const int hi = hi0 + kh;
            const bool rowok = (unsigned)hi < (unsigned)HIN;
            const float* xr = xc + (size_t)(rowok ? hi : 0) * WIN;
            float r[G::L];
#pragma unroll
            for (int u = 0; u < G::L; ++u) {
                const int wi = wi0 + u;
                const bool ok = rowok && (unsigned)wi < (unsigned)WIN;
                const float v = xr[ok ? wi : 0];
                r[u] = ok ? v : 0.0f;
            }
#pragma unroll
            for (int kw = 0; kw < K; ++kw) {
                const float* wg = wc + (kh * K + kw) * TCO;
                float w8[TCO];
#pragma unroll
                for (int t = 0; t < TCO; ++t) w8[t] = wg[t];
#pragma unroll
                for (int j = 0; j < TW; ++j) {
                    const float xv = r[kw + j * S];
#pragma unroll
                    for (int t = 0; t < TCO; ++t)
                        acc[t][j] = fmaf(xv, w8[t], acc[t][j]);
                }
            }
        }
    }

#pragma unroll
    for (int t = 0; t < TCO; ++t) {
        float* yr = y + (size_t)(b * COUT + cob + t) * OPLANE
                      + (size_t)(ho + 1) * OSTR + wo + 4;
#pragma unroll
        for (int j = 0; j < TW; ++j) {
            const float v = acc[t][j];
            yr[j] = v >= 0.0f ? v : NEG_SLOPE * v;
        }
    }
}

// ---------------- bilinear warp (B=4, H=12, W=24; compact input) ----------------
__global__ void warp_kernel(const float* __restrict__ img, const float* __restrict__ flow,
                            float* __restrict__ out, int C) {
    const int H = 12, W = 24, HW = 288;
    int idx = blockIdx.x * blockDim.x + threadIdx.x;
    int total = 4 * C * HW;
    if (idx >= total) return;
    int w = idx % W;
    int h = (idx / W) % H;
    int c = (idx / HW) % C;
    int b = idx / (HW * C);

    float fx = flow[(((size_t)b * 2 + 0) * H + h) * W + w] * 0.625f;
    float fy = flow[(((size_t)b * 2 + 1) * H + h) * W + w] * 0.625f;
    float px = (float)w + fx;
    float py = (float)h + fy;
    float x0f = floorf(px);
    float y0f = floorf(py);
    float wx = px - x0f;
    float wy = py - y0f;
    int x0 = (int)x0f;
    int y0 = (int)y0f;

    const float* ip = img + ((size_t)b * C + c) * HW;
    auto g = [&](int yi, int xi) -> float {
        if (xi < 0 || xi > W - 1 || yi < 0 || yi > H - 1) return 0.0f;
        return ip[yi * W + xi];
    };
    float v = g(y0, x0) * (1.0f - wx) * (1.0f - wy)
            + g(y0, x0 + 1) * wx * (1.0f - wy)
            + g(y0 + 1, x0) * (1.0f - wx) * wy
            + g(y0 + 1, x0 + 1) * wx * wy;
    out[idx] = v;
}

// ---------------- correlation (7x7 disp) + lrelu ----------------
__global__ void corr_lrelu(const float* __restrict__ f1, const float* __restrict__ wp,
                           float* __restrict__ out, int C) {
    const int H = 12, W = 24, HW = 288;
    int idx = blockIdx.x * blockDim.x + threadIdx.x;
    int total = 4 * 49 * HW;
    if (idx >= total) return;
    int w = idx % W;
    int h = (idx / W) % H;
    int d = (idx / HW) % 49;
    int b = idx / (49 * HW);
    int di = d / 7 - 3;
    int dj = d % 7 - 3;
    int h2 = h + di;
    int w2 = w + dj;

    float s = 0.0f;
    if (h2 >= 0 && h2 < H && w2 >= 0 && w2 < W) {
        const float* a = f1 + (size_t)b * C * HW + h * W + w;
        const float* p = wp + (size_t)b * C * HW + h2 * W + w2;
        for (int c = 0; c < C; ++c) s = fmaf(a[(size_t)c * HW], p[(size_t)c * HW], s);
    }
    s /= (float)C;
    s = (s >= 0.0f) ? s : NEG_SLOPE * s;
    out[idx] = s;
}

// ---------------- host ----------------
template <int K, int S, int PAD, int CIN, int COUT,
          int HIN, int WIN, int HOUT, int WOUT, int TCO, int TW, int NB, bool POUT>
static void launch_pad(const float* x, const float* w, const float* bs, float* y,
                       hipStream_t stream) {
    constexpr int NSLOT = HOUT * (WOUT / TW);
    constexpr int NBLK  = (NSLOT + 255) / 256;
    conv_pad<K, S, PAD, CIN, COUT, HIN, WIN, HOUT, WOUT, TCO, TW, NB, POUT>
        <<<dim3(NBLK * NB, 1, COUT / TCO), 256, 0, stream>>>(x, w, bs, y);
}

static void launch_ring(float* buf, int nplanes, int PH, int PW, hipStream_t stream) {
    const int total = nplanes * (2 * PW + (PH - 2) * 8);
    ring_zero<<<cdiv(total, 256), 256, 0, stream>>>(buf, nplanes, PH, PW);
}

// Workspace plan (39.6M floats of the proven 47.85M):
//   A = ws[0          : 19,468,288)  L1-out pad (half-batch, 64 planes 386x776)
//                                    then L3/L5/L7/L9-out pad (batch-8)
//   B = ws[19,468,288 : 38,936,576)  L2/L4/L6/L8-out pad (batch-8)
//   F12 = ws[38,936,576 : 39,378,944) compact L10 out (b0-3=img1, b4-7=img2)
//   WRP = ws[39,378,944 : 39,600,128)
extern "C" void kernel_launch(void* const* d_in, const int* in_sizes, int n_in,
                              void* d_out, int out_size, void* d_ws, size_t ws_size,
                              hipStream_t stream) {
    const float* img1 = (const float*)d_in[0];
    const float* img2 = (const float*)d_in[1];
    const float* flow = (const float*)d_in[2];
    float* out = (float*)d_out;

    const float* W[10];
    const float* Bs[10];
    for (int l = 0; l < 10; ++l) {
        W[l]  = (const float*)d_in[3 + 2 * l];
        Bs[l] = (const float*)d_in[4 + 2 * l];
    }

    float* ws  = (float*)d_ws;
    float* A   = ws;
    float* B   = ws + 19468288;
    float* F12 = ws + 38936576;
    float* WRP = ws + 39378944;

    using G1 = Geom<7,1,3, 384,768, 384,768, 4>;

    // rings that must be zero before first use (A: L1-out geom, B: L2-out geom).
    launch_ring(A,  64, 386, 776, stream);
    launch_ring(B, 256, 194, 392, stream);

    // ---- L1+L2 at half-batch (2 images x 2 halves); L1 kernels untouched. ----
    const size_t IMG_HALF     = 2ull * 3 * 384 * 768;
    const size_t L2O_QUARTER  = 2ull * 32 * 194 * 392;   // 4,867,072

    const float* imgs[2] = { img1, img2 };
    for (int i = 0; i < 2; ++i) {
        for (int h = 0; h < 2; ++h) {
            const float* xin = imgs[i] + (size_t)h * IMG_HALF;
            float* qout = B + ((size_t)i * 2 + h) * L2O_QUARTER;
            conv_int<7,1,3,  3, 32, 384,768, 384,768, 8,4>
                <<<dim3(cdiv(G1::N_INT, 256), 1, 2*(32/8)), 256, 0, stream>>>(xin, W[0], Bs[0], A);
            conv_edge<7,1,3,  3, 32, 384,768, 384,768, 8,4>
                <<<dim3(cdiv(G1::N_EDGE, 256), 1, 2*(32/8)), 256, 0, stream>>>(xin, W[0], Bs[0], A);
            launch_pad<3,2,1, 32, 32, 384,768, 192,384, 8,4, 2, true>(A, W[1], Bs[1], qout, stream);
        }
    }

    // ---- L3..L10 at batch-8 (NB=8 folded into x -> per-XCD batch partition) ----
    launch_ring(A, 256, 194, 392, stream);                                    // for L3 out
    launch_pad<3,1,1, 32, 32, 192,384, 192,384, 8,4, 8, true >(B, W[2], Bs[2], A,   stream);
    launch_pad<3,1,1, 32, 32, 192,384, 192,384, 8,4, 8, true >(A, W[3], Bs[3], B,   stream);
    launch_ring(A, 512, 98, 200, stream);                                     // for L5 out
    launch_pad<3,2,1, 32, 64, 192,384,  96,192, 8,4, 8, true >(B, W[4], Bs[4], A,   stream);
    launch_ring(B, 512, 98, 200, stream);                                     // for L6 out
    launch_pad<3,1,1, 64, 64,  96,192,  96,192, 8,4, 8, true >(A, W[5], Bs[5], B,   stream);
    launch_ring(A, 768, 50, 104, stream);                                     // for L7 out
    launch_pad<3,2,1, 64, 96,  96,192,  48, 96, 8,4, 8, true >(B, W[6], Bs[6], A,   stream);
    launch_ring(B, 768, 50, 104, stream);                                     // for L8 out
    launch_pad<3,1,1, 96, 96,  48, 96,  48, 96, 8,4, 8, true >(A, W[7], Bs[7], B,   stream);
    launch_ring(A, 1024, 26, 56, stream);                                     // for L9 out
    launch_pad<3,2,1, 96,128,  48, 96,  24, 48, 8,4, 8, true >(B, W[8], Bs[8], A,   stream);
    launch_pad<3,2,1,128,192,  24, 48,  12, 24, 4,2, 8, false>(A, W[9], Bs[9], F12, stream);

    // ---- warp + correlation (compact F12) ----
    float* f1 = F12;               // batches 0..3 = img1 features
    float* f2 = F12 + 221184;      // batches 4..7 = img2 features
    warp_kernel<<<cdiv(4 * 192 * 288, 256), 256, 0, stream>>>(f2, flow, WRP, 192);
    corr_lrelu<<<cdiv(4 * 49 * 288, 256), 256, 0, stream>>>(f1, WRP, out, 192);
}

// Round 17
// 1673.583 us; speedup vs baseline: 1.0427x; 1.0427x over previous
//
#include <hip/hip_runtime.h>

#define NEG_SLOPE 0.1f

static inline int cdiv(int a, int b) { return (a + b - 1) / b; }

// ======================= padded-buffer conv scheme =======================
// All intermediate tensors live in a padded layout: per (b,c) plane of logical
// H x W data, physical plane is (H+2) rows x (W+8) cols; element (h,w) at
// [(h+1)*(W+8) + (w+4)]. The 1-row/4-col ring holds zeros (maintained by
// ring_zero), so EVERY conv output slot reads unconditionally — one interior
// body (VGPR 32, measured) covers 100% of the work, no edge kernel.
// W+8 keeps row stride and store base multiples of 4 floats -> float4 stores.
//
// FINAL (round-17): byte-exact round-15 artifact — session best, measured
// 1678.7us / 1680.1us on two independent runs (baseline was 3136us, -46.5%).
// The tuning families are closed by counter-verified null results:
//   r10 LDS-issue/4=flat, r11 occupancy x2=+23%, r12 unroll=+6%,
//   r13/r14 reuse-tiling=flat, r16 HBM-traffic/2.5 (XCD partition)=flat.
// The dominant dispatches are issue-mix bound (FMA+addr-VALU+LDS+VMEM each
// sub-dominant; VALUBusy ~58%, HBM ~12%); progress past this requires an
// implicit-GEMM/LDS-staged rewrite or low-precision MFMA (no fp32 MFMA on
// CDNA4), both outside safe reach of this session's remaining budget.

// ---------------- ring_zero: zero the pad ring of nplanes planes ----------------
__global__ void ring_zero(float* __restrict__ buf, int nplanes, int PH, int PW) {
    const int R = 2 * PW + (PH - 2) * 8;       // ring elems per plane
    const int total = nplanes * R;
    int idx = blockIdx.x * 256 + threadIdx.x;
    if (idx >= total) return;
    int p = idx / R, r = idx % R;
    int row, col;
    if (r < PW)           { row = 0;        col = r; }
    else if (r < 2 * PW)  { row = PH - 1;   col = r - PW; }
    else {
        int rr = r - 2 * PW;
        row = 1 + rr / 8;
        int c = rr % 8;
        col = (c < 4) ? c : (PW - 8 + c);      // left 4 cols, right 4 cols
    }
    buf[(size_t)p * PH * PW + (size_t)row * PW + col] = 0.0f;
}

// ---------------- conv over padded input (single interior-style body) -----------
// POUT: write into padded layout (next layer's input) or compact (final features).
template <int K, int S, int PAD, int CIN, int COUT,
          int HIN, int WIN, int HOUT, int WOUT, int TCO, int TW, bool POUT>
__global__ __launch_bounds__(256) void conv_pad(const float* __restrict__ x,
                                                const float* __restrict__ w,
                                                const float* __restrict__ bs,
                                                float* __restrict__ y) {
    constexpr int SLOTS_W = WOUT / TW;
    constexpr int NSLOT   = HOUT * SLOTS_W;
    constexpr int NW      = TCO * CIN * K * K;
    constexpr int L       = (TW - 1) * S + K;
    constexpr int ISTR    = WIN + 8;
    constexpr int IPLANE  = (HIN + 2) * ISTR;
    constexpr int OSTR    = POUT ? (WOUT + 8) : WOUT;
    constexpr int OPLANE  = POUT ? (HOUT + 2) * OSTR : HOUT * WOUT;

    __shared__ float wlds[NW];

    const int zz  = blockIdx.z;
    const int b   = zz / (COUT / TCO);
    const int cob = (zz % (COUT / TCO)) * TCO;

    for (int i = threadIdx.x; i < NW; i += 256) {
        int t    = i % TCO;
        int rest = i / TCO;
        wlds[i] = w[(size_t)(cob + t) * (CIN * K * K) + rest];
    }
    __syncthreads();

    const int slot = blockIdx.x * 256 + threadIdx.x;
    if (slot >= NSLOT) return;

    const int ho = slot / SLOTS_W;
    const int wo = (slot % SLOTS_W) * TW;

    const float* xb = x + (size_t)b * CIN * IPLANE;

    float acc[TCO][TW];
#pragma unroll
    for (int t = 0; t < TCO; ++t) {
        float bv = bs[cob + t];
#pragma unroll
        for (int j = 0; j < TW; ++j) acc[t][j] = bv;
    }

    const int hi0 = ho * S - PAD;   // may be -1: row 0 of padded plane (zeros)
    const int wi0 = wo * S - PAD;

    for (int ci = 0; ci < CIN; ++ci) {
        const float* xc = xb + (size_t)ci * IPLANE;
        const float* wc = &wlds[(ci * K * K) * TCO];
#pragma unroll
        for (int kh = 0; kh < K; ++kh) {
            const float* xr = xc + (size_t)(hi0 + kh + 1) * ISTR + (wi0 + 4);
            float r[L];
#pragma unroll
            for (int u = 0; u < L; ++u) r[u] = xr[u];
#pragma unroll
            for (int kw = 0; kw < K; ++kw) {
                const float* wg = wc + (kh * K + kw) * TCO;
                float w8[TCO];
                if constexpr ((TCO % 4) == 0) {
#pragma unroll
                    for (int t = 0; t < TCO; t += 4) {
                        float4 q = *reinterpret_cast<const float4*>(wg + t);
                        w8[t] = q.x; w8[t + 1] = q.y; w8[t + 2] = q.z; w8[t + 3] = q.w;
                    }
                } else {
#pragma unroll
                    for (int t = 0; t < TCO; ++t) w8[t] = wg[t];
                }
#pragma unroll
                for (int j = 0; j < TW; ++j) {
                    const float xv = r[kw + j * S];
#pragma unroll
                    for (int t = 0; t < TCO; ++t)
                        acc[t][j] = fmaf(xv, w8[t], acc[t][j]);
                }
            }
        }
    }

#pragma unroll
    for (int t = 0; t < TCO; ++t) {
        float* yr = y + (size_t)(b * COUT + cob + t) * OPLANE
                      + (POUT ? ((size_t)(ho + 1) * OSTR + wo + 4)
                              : ((size_t)ho * WOUT + wo));
        float v[TW];
#pragma unroll
        for (int j = 0; j < TW; ++j) {
            const float a = acc[t][j];
            v[j] = a >= 0.0f ? a : NEG_SLOPE * a;
        }
        if constexpr (TW == 4) {
            *reinterpret_cast<float4*>(yr) = make_float4(v[0], v[1], v[2], v[3]);
        } else if constexpr (TW == 2) {
            *reinterpret_cast<float2*>(yr) = make_float2(v[0], v[1]);
        } else {
#pragma unroll
            for (int j = 0; j < TW; ++j) yr[j] = v[j];
        }
    }
}

// Compile-time geometry for L1 (reads the raw, unpadded image).
template <int K, int S, int PAD, int HIN, int WIN, int HOUT, int WOUT, int TW>
struct Geom {
    static constexpr int SLOTS_W = WOUT / TW;
    static constexpr int NSLOT   = HOUT * SLOTS_W;
    static constexpr int L       = (TW - 1) * S + K;
    static constexpr int HO_LO   = (PAD + S - 1) / S;
    static constexpr int HO_HI0  = (HIN - K + PAD) / S + 1;
    static constexpr int HO_HI   = HO_HI0 < HOUT ? HO_HI0 : HOUT;
    static constexpr int WS_LO   = (PAD + TW * S - 1) / (TW * S);
    static constexpr int WS_HI0  = (WIN + PAD - L) / (TW * S) + 1;
    static constexpr int WS_HI   = WS_HI0 < SLOTS_W ? WS_HI0 : SLOTS_W;
    static constexpr int WS_N    = WS_HI - WS_LO;
    static constexpr int N_INT   = (HO_HI - HO_LO) * WS_N;
    static constexpr int N_EDGE  = NSLOT - N_INT;
};

// ---------------- L1 interior (round-3 body; padded store) -------
template <int K, int S, int PAD, int CIN, int COUT,
          int HIN, int WIN, int HOUT, int WOUT, int TCO, int TW>
__global__ __launch_bounds__(256, 4) void conv_int(const float* __restrict__ x,
                                                   const float* __restrict__ w,
                                                   const float* __restrict__ bs,
                                                   float* __restrict__ y) {
    using G = Geom<K, S, PAD, HIN, WIN, HOUT, WOUT, TW>;
    constexpr int NW     = TCO * CIN * K * K;
    constexpr int OSTR   = WOUT + 8;
    constexpr int OPLANE = (HOUT + 2) * OSTR;

    __shared__ float wlds[NW];

    const int zz  = blockIdx.z;
    const int b   = zz / (COUT / TCO);
    const int cob = (zz % (COUT / TCO)) * TCO;

    for (int i = threadIdx.x; i < NW; i += 256) {
        int t    = i % TCO;
        int rest = i / TCO;
        wlds[i] = w[(size_t)(cob + t) * (CIN * K * K) + rest];
    }
    __syncthreads();

    const int s = blockIdx.x * 256 + threadIdx.x;
    if (s >= G::N_INT) return;

    const int ho = G::HO_LO + s / G::WS_N;
    const int wo = (G::WS_LO + s % G::WS_N) * TW;

    const float* xb = x + (size_t)b * CIN * HIN * WIN;

    float acc[TCO][TW];
#pragma unroll
    for (int t = 0; t < TCO; ++t) {
        float bv = bs[cob + t];
#pragma unroll
        for (int j = 0; j < TW; ++j) acc[t][j] = bv;
    }

    const int hi0 = ho * S - PAD;
    const int wi0 = wo * S - PAD;

#pragma unroll
    for (int ci = 0; ci < CIN; ++ci) {
        const float* xc = xb + (size_t)ci * HIN * WIN;
        const float* wc = &wlds[(ci * K * K) * TCO];
#pragma unroll
        for (int kh = 0; kh < K; ++kh) {
            const float* xr = xc + (size_t)(hi0 + kh) * WIN + wi0;
            float r[G::L];
#pragma unroll
            for (int u = 0; u < G::L; ++u) r[u] = xr[u];
#pragma unroll
            for (int kw = 0; kw < K; ++kw) {
                const float* wg = wc + (kh * K + kw) * TCO;
                float w8[TCO];
                if constexpr ((TCO % 4) == 0) {
#pragma unroll
                    for (int t = 0; t < TCO; t += 4) {
                        float4 q = *reinterpret_cast<const float4*>(wg + t);
                        w8[t] = q.x; w8[t + 1] = q.y; w8[t + 2] = q.z; w8[t + 3] = q.w;
                    }
                } else {
#pragma unroll
                    for (int t = 0; t < TCO; ++t) w8[t] = wg[t];
                }
#pragma unroll
                for (int j = 0; j < TW; ++j) {
                    const float xv = r[kw + j * S];
#pragma unroll
                    for (int t = 0; t < TCO; ++t)
                        acc[t][j] = fmaf(xv, w8[t], acc[t][j]);
                }
            }
        }
    }

#pragma unroll
    for (int t = 0; t < TCO; ++t) {
        float* yr = y + (size_t)(b * COUT + cob + t) * OPLANE
                      + (size_t)(ho + 1) * OSTR + wo + 4;
        float v[TW];
#pragma unroll
        for (int j = 0; j < TW; ++j) {
            const float a = acc[t][j];
            v[j] = a >= 0.0f ? a : NEG_SLOPE * a;
        }
        if constexpr (TW == 4) {
            *reinterpret_cast<float4*>(yr) = make_float4(v[0], v[1], v[2], v[3]);
        } else {
#pragma unroll
            for (int j = 0; j < TW; ++j) yr[j] = v[j];
        }
    }
}

// ---------------- L1 edge ring (bounds-checked reads; padded store) ----------------
template <int K, int S, int PAD, int CIN, int COUT,
          int HIN, int WIN, int HOUT, int WOUT, int TCO, int TW>
__global__ __launch_bounds__(256) void conv_edge(const float* __restrict__ x,
                                                 const float* __restrict__ w,
                                                 const float* __restrict__ bs,
                                                 float* __restrict__ y) {
    using G = Geom<K, S, PAD, HIN, WIN, HOUT, WOUT, TW>;
    constexpr int SLOTS_W = G::SLOTS_W;
    constexpr int NW      = TCO * CIN * K * K;
    constexpr int OSTR    = WOUT + 8;
    constexpr int OPLANE  = (HOUT + 2) * OSTR;

    __shared__ float wlds[NW];

    const int zz  = blockIdx.z;
    const int b   = zz / (COUT / TCO);
    const int cob = (zz % (COUT / TCO)) * TCO;

    for (int i = threadIdx.x; i < NW; i += 256) {
        int t    = i % TCO;
        int rest = i / TCO;
        wlds[i] = w[(size_t)(cob + t) * (CIN * K * K) + rest];
    }
    __syncthreads();

    const int s = blockIdx.x * 256 + threadIdx.x;
    if (s >= G::N_EDGE) return;

    constexpr int TOPN = G::HO_LO * SLOTS_W;
    constexpr int BOTN = (HOUT - G::HO_HI) * SLOTS_W;
    constexpr int MIDH = G::HO_HI - G::HO_LO;
    constexpr int LW   = G::WS_LO;
    constexpr int RW   = SLOTS_W - G::WS_HI;
    constexpr int LN   = MIDH * LW;

    int ho = 0, ws = 0;
    if (s < TOPN) {
        ho = s / SLOTS_W;
        ws = s % SLOTS_W;
    } else if (s < TOPN + BOTN) {
        int t = s - TOPN;
        ho = G::HO_HI + t / SLOTS_W;
        ws = t % SLOTS_W;
    } else if (s < TOPN + BOTN + LN) {
        int t = s - TOPN - BOTN;
        constexpr int D = LW > 0 ? LW : 1;
        ho = G::HO_LO + t / D;
        ws = t % D;
    } else {
        int t = s - TOPN - BOTN - LN;
        constexpr int D = RW > 0 ? RW : 1;
        ho = G::HO_LO + t / D;
        ws = G::WS_HI + t % D;
    }
    const int wo = ws * TW;

    const float* xb = x + (size_t)b * CIN * HIN * WIN;

    float acc[TCO][TW];
#pragma unroll
    for (int t = 0; t < TCO; ++t) {
        float bv = bs[cob + t];
#pragma unroll
        for (int j = 0; j < TW; ++j) acc[t][j] = bv;
    }

    const int hi0 = ho * S - PAD;
    const int wi0 = wo * S - PAD;

#pragma unroll 2
    for (int ci = 0; ci < CIN; ++ci) {
        const float* xc = xb + (size_t)ci * HIN * WIN;
        const float* wc = &wlds[(ci * K * K) * TCO];
#pragma unroll
        for (int kh = 0; kh < K; ++kh) {
            const int hi = hi0 + kh;
            const bool rowok = (unsigned)hi < (unsigned)HIN;
            const float* xr = xc + (size_t)(rowok ? hi : 0) * WIN;
            float r[G::L];
#pragma unroll
            for (int u = 0; u < G::L; ++u) {
                const int wi = wi0 + u;
                const bool ok = rowok && (unsigned)wi < (unsigned)WIN;
                const float v = xr[ok ? wi : 0];
                r[u] = ok ? v : 0.0f;
            }
#pragma unroll
            for (int kw = 0; kw < K; ++kw) {
                const float* wg = wc + (kh * K + kw) * TCO;
                float w8[TCO];
#pragma unroll
                for (int t = 0; t < TCO; ++t) w8[t] = wg[t];
#pragma unroll
                for (int j = 0; j < TW; ++j) {
                    const float xv = r[kw + j * S];
#pragma unroll
                    for (int t = 0; t < TCO; ++t)
                        acc[t][j] = fmaf(xv, w8[t], acc[t][j]);
                }
            }
        }
    }

#pragma unroll
    for (int t = 0; t < TCO; ++t) {
        float* yr = y + (size_t)(b * COUT + cob + t) * OPLANE
                      + (size_t)(ho + 1) * OSTR + wo + 4;
#pragma unroll
        for (int j = 0; j < TW; ++j) {
            const float v = acc[t][j];
            yr[j] = v >= 0.0f ? v : NEG_SLOPE * v;
        }
    }
}

// ---------------- bilinear warp (B=4, H=12, W=24; compact input) ----------------
__global__ void warp_kernel(const float* __restrict__ img, const float* __restrict__ flow,
                            float* __restrict__ out, int C) {
    const int H = 12, W = 24, HW = 288;
    int idx = blockIdx.x * blockDim.x + threadIdx.x;
    int total = 4 * C * HW;
    if (idx >= total) return;
    int w = idx % W;
    int h = (idx / W) % H;
    int c = (idx / HW) % C;
    int b = idx / (HW * C);

    float fx = flow[(((size_t)b * 2 + 0) * H + h) * W + w] * 0.625f;
    float fy = flow[(((size_t)b * 2 + 1) * H + h) * W + w] * 0.625f;
    float px = (float)w + fx;
    float py = (float)h + fy;
    float x0f = floorf(px);
    float y0f = floorf(py);
    float wx = px - x0f;
    float wy = py - y0f;
    int x0 = (int)x0f;
    int y0 = (int)y0f;

    const float* ip = img + ((size_t)b * C + c) * HW;
    auto g = [&](int yi, int xi) -> float {
        if (xi < 0 || xi > W - 1 || yi < 0 || yi > H - 1) return 0.0f;
        return ip[yi * W + xi];
    };
    float v = g(y0, x0) * (1.0f - wx) * (1.0f - wy)
            + g(y0, x0 + 1) * wx * (1.0f - wy)
            + g(y0 + 1, x0) * (1.0f - wx) * wy
            + g(y0 + 1, x0 + 1) * wx * wy;
    out[idx] = v;
}

// ---------------- correlation (7x7 disp) + lrelu ----------------
__global__ void corr_lrelu(const float* __restrict__ f1, const float* __restrict__ wp,
                           float* __restrict__ out, int C) {
    const int H = 12, W = 24, HW = 288;
    int idx = blockIdx.x * blockDim.x + threadIdx.x;
    int total = 4 * 49 * HW;
    if (idx >= total) return;
    int w = idx % W;
    int h = (idx / W) % H;
    int d = (idx / HW) % 49;
    int b = idx / (49 * HW);
    int di = d / 7 - 3;
    int dj = d % 7 - 3;
    int h2 = h + di;
    int w2 = w + dj;

    float s = 0.0f;
    if (h2 >= 0 && h2 < H && w2 >= 0 && w2 < W) {
        const float* a = f1 + (size_t)b * C * HW + h * W + w;
        const float* p = wp + (size_t)b * C * HW + h2 * W + w2;
        for (int c = 0; c < C; ++c) s = fmaf(a[(size_t)c * HW], p[(size_t)c * HW], s);
    }
    s /= (float)C;
    s = (s >= 0.0f) ? s : NEG_SLOPE * s;
    out[idx] = s;
}

// ---------------- host ----------------
template <int K, int S, int PAD, int CIN, int COUT,
          int HIN, int WIN, int HOUT, int WOUT, int TCO, int TW, bool POUT>
static void launch_pad(const float* x, const float* w, const float* bs, float* y,
                       int nb, hipStream_t stream) {
    constexpr int NSLOT = HOUT * (WOUT / TW);
    const int z = nb * (COUT / TCO);
    conv_pad<K, S, PAD, CIN, COUT, HIN, WIN, HOUT, WOUT, TCO, TW, POUT>
        <<<dim3(cdiv(NSLOT, 256), 1, z), 256, 0, stream>>>(x, w, bs, y);
}

static void launch_ring(float* buf, int nplanes, int PH, int PW, hipStream_t stream) {
    const int total = nplanes * (2 * PW + (PH - 2) * 8);
    ring_zero<<<cdiv(total, 256), 256, 0, stream>>>(buf, nplanes, PH, PW);
}

// Workspace plan (39.6M floats of the proven 47.85M):
//   A = ws[0          : 19,468,288)  L1-out pad (half-batch, 64 planes 386x776)
//                                    then L3/L5/L7/L9-out pad (batch-8)
//   B = ws[19,468,288 : 38,936,576)  L2/L4/L6/L8-out pad (batch-8)
//   F12 = ws[38,936,576 : 39,378,944) compact L10 out (b0-3=img1, b4-7=img2)
//   WRP = ws[39,378,944 : 39,600,128)
extern "C" void kernel_launch(void* const* d_in, const int* in_sizes, int n_in,
                              void* d_out, int out_size, void* d_ws, size_t ws_size,
                              hipStream_t stream) {
    const float* img1 = (const float*)d_in[0];
    const float* img2 = (const float*)d_in[1];
    const float* flow = (const float*)d_in[2];
    float* out = (float*)d_out;

    const float* W[10];
    const float* Bs[10];
    for (int l = 0; l < 10; ++l) {
        W[l]  = (const float*)d_in[3 + 2 * l];
        Bs[l] = (const float*)d_in[4 + 2 * l];
    }

    float* ws  = (float*)d_ws;
    float* A   = ws;
    float* B   = ws + 19468288;
    float* F12 = ws + 38936576;
    float* WRP = ws + 39378944;

    using G1 = Geom<7,1,3, 384,768, 384,768, 4>;

    // rings that must be zero before first use (A: L1-out geom, B: L2-out geom).
    launch_ring(A,  64, 386, 776, stream);
    launch_ring(B, 256, 194, 392, stream);

    // ---- L1+L2 at half-batch (2 images x 2 halves); A's interior rewritten each pass,
    //      ring stays zero. L2 output lands in B quarters (padded batch-8 layout). ----
    const size_t IMG_HALF     = 2ull * 3 * 384 * 768;
    const size_t L2O_QUARTER  = 2ull * 32 * 194 * 392;   // 4,867,072

    const float* imgs[2] = { img1, img2 };
    for (int i = 0; i < 2; ++i) {
        for (int h = 0; h < 2; ++h) {
            const float* xin = imgs[i] + (size_t)h * IMG_HALF;
            float* qout = B + ((size_t)i * 2 + h) * L2O_QUARTER;
            conv_int<7,1,3,  3, 32, 384,768, 384,768, 8,4>
                <<<dim3(cdiv(G1::N_INT, 256), 1, 2*(32/8)), 256, 0, stream>>>(xin, W[0], Bs[0], A);
            conv_edge<7,1,3,  3, 32, 384,768, 384,768, 8,4>
                <<<dim3(cdiv(G1::N_EDGE, 256), 1, 2*(32/8)), 256, 0, stream>>>(xin, W[0], Bs[0], A);
            launch_pad<3,2,1, 32, 32, 384,768, 192,384, 8,4, true>(A, W[1], Bs[1], qout, 2, stream);
        }
    }

    // ---- L3..L10 at batch-8; ring-zero the write target (new geometry) just before
    //      each conv, after the previous reader of that buffer. ----
    launch_ring(A, 256, 194, 392, stream);                                    // for L3 out
    launch_pad<3,1,1, 32, 32, 192,384, 192,384, 8,4, true >(B, W[2], Bs[2], A,   8, stream);
    launch_pad<3,1,1, 32, 32, 192,384, 192,384, 8,4, true >(A, W[3], Bs[3], B,   8, stream);
    launch_ring(A, 512, 98, 200, stream);                                     // for L5 out
    launch_pad<3,2,1, 32, 64, 192,384,  96,192, 8,4, true >(B, W[4], Bs[4], A,   8, stream);
    launch_ring(B, 512, 98, 200, stream);                                     // for L6 out
    launch_pad<3,1,1, 64, 64,  96,192,  96,192, 8,4, true >(A, W[5], Bs[5], B,   8, stream);
    launch_ring(A, 768, 50, 104, stream);                                     // for L7 out
    launch_pad<3,2,1, 64, 96,  96,192,  48, 96, 8,4, true >(B, W[6], Bs[6], A,   8, stream);
    launch_ring(B, 768, 50, 104, stream);                                     // for L8 out
    launch_pad<3,1,1, 96, 96,  48, 96,  48, 96, 8,4, true >(A, W[7], Bs[7], B,   8, stream);
    launch_ring(A, 1024, 26, 56, stream);                                     // for L9 out
    launch_pad<3,2,1, 96,128,  48, 96,  24, 48, 8,4, true >(B, W[8], Bs[8], A,   8, stream);
    // L10: TCO=4/TW=2 -> 144-thread block fill (was 72/256) and 2x z-blocks.
    launch_pad<3,2,1,128,192,  24, 48,  12, 24, 4,2, false>(A, W[9], Bs[9], F12, 8, stream);

    // ---- warp + correlation (compact F12) ----
    float* f1 = F12;               // batches 0..3 = img1 features
    float* f2 = F12 + 221184;      // batches 4..7 = img2 features
    warp_kernel<<<cdiv(4 * 192 * 288, 256), 256, 0, stream>>>(f2, flow, WRP, 192);
    corr_lrelu<<<cdiv(4 * 49 * 288, 256), 256, 0, stream>>>(f1, WRP, out, 192);
}